// Round 14
// baseline (189.548 us; speedup 1.0000x reference)
//
#include <hip/hip_runtime.h>
#include <hip/hip_bf16.h>

typedef __attribute__((ext_vector_type(8))) short short8;
typedef __attribute__((ext_vector_type(4))) float floatx4;

#define F_IN 256
#define F_OUT 128
#define NODE_SHIFT 8               // 256 nodes per coarse bucket
#define BKT_NODES 256
#define QTR_NODES 64               // agg works on 64-node quarters
#define MAX_BKT 2048
#define AGG_THREADS 512
#define AGG_CAP 4096               // max edges per QUARTER on LDS-sort path (mean 1024)
#define FILL_BLOCKS 128
#define FILL_THREADS 512
#define GEMM_THREADS 256

static __device__ __forceinline__ short f32_to_bf16_bits(float v) {
    __hip_bfloat16 t = __float2bfloat16(v);
    return *reinterpret_cast<short*>(&t);
}
static __device__ __forceinline__ float bf16bits_to_f32(unsigned short u) {
    unsigned x = (unsigned)u << 16;
    return __builtin_bit_cast(float, x);
}

// Deterministic input-dtype probe + zero bucket_counts + zero done-counter.
// flags[0]: 1 = floats are f32, 0 = bf16;  flags[1]: 1 = int64 idx, 0 = int32
// flags[8]: done-counter for the fused scan
__global__ __launch_bounds__(256) void detect_kernel(
    const void* __restrict__ featp, const void* __restrict__ dstp,
    int* __restrict__ flags, int* __restrict__ bucket_counts, int nbkt)
{
    for (int j = threadIdx.x; j < nbkt; j += 256) bucket_counts[j] = 0;
    if (threadIdx.x == 0) {
        const unsigned short* fb = (const unsigned short*)featp;
        int plaus = 0;
        for (int i = 0; i < 64; ++i) {
            unsigned short u = fb[2 * i];
            int ex = (u >> 7) & 0xFF;
            if (ex >= 118 && ex <= 137) plaus++;
        }
        flags[0] = (plaus >= 48) ? 0 : 1;

        const int* di = (const int*)dstp;
        int zeros = 0;
        for (int i = 0; i < 64; ++i)
            if (di[2 * i + 1] == 0) zeros++;
        flags[1] = (zeros >= 62) ? 1 : 0;
        flags[8] = 0;   // done counter
    }
}

// LDS-histogram of dst>>NODE_SHIFT, global merge; the LAST block to finish
// scans counts -> offsets+cursor (r9-proven handoff). 512 blocks for TLP.
__global__ __launch_bounds__(256) void bincount_scan_kernel(
    const void* __restrict__ dstp, int* __restrict__ bucket_counts,
    int* __restrict__ offsets, int* __restrict__ cursor,
    int n_edges, int n_nodes, int nbkt, int* __restrict__ flags)
{
    const int i64 = flags[1];
    __shared__ int hist[MAX_BKT];
    __shared__ int is_last;
    const bool use_lds = (nbkt <= MAX_BKT);
    if (use_lds) {
        for (int j = threadIdx.x; j < nbkt; j += 256) hist[j] = 0;
        __syncthreads();
    }
    const int stride = gridDim.x * blockDim.x;
    for (int e = blockIdx.x * blockDim.x + threadIdx.x; e < n_edges; e += stride) {
        int d = i64 ? (int)((const long long*)dstp)[e] : ((const int*)dstp)[e];
        if ((unsigned)d >= (unsigned)n_nodes) continue;
        if (use_lds) atomicAdd(&hist[d >> NODE_SHIFT], 1);
        else         atomicAdd(&bucket_counts[d >> NODE_SHIFT], 1);
    }
    if (use_lds) {
        __syncthreads();
        for (int j = threadIdx.x; j < nbkt; j += 256) {
            int c = hist[j];
            if (c) atomicAdd(&bucket_counts[j], c);
        }
    }
    __threadfence();
    if (threadIdx.x == 0)
        is_last = (atomicAdd(&flags[8], 1) == (int)gridDim.x - 1);
    __syncthreads();
    if (!is_last) return;

    // exclusive scan (nbkt <= 4096), hist[] as scratch
    const int t = threadIdx.x;
    const int base = t * 16;
    int v[16];
    int run = 0;
#pragma unroll
    for (int j = 0; j < 16; ++j) {
        int idx = base + j;
        int x = (idx < nbkt)
            ? __hip_atomic_load(&bucket_counts[idx], __ATOMIC_RELAXED,
                                __HIP_MEMORY_SCOPE_AGENT)
            : 0;
        v[j] = run;
        run += x;
    }
    __syncthreads();
    hist[t] = run;
    __syncthreads();
    for (int off = 1; off < 256; off <<= 1) {
        int x = (t >= off) ? hist[t - off] : 0;
        __syncthreads();
        hist[t] += x;
        __syncthreads();
    }
    const int excl = hist[t] - run;
#pragma unroll
    for (int j = 0; j < 16; ++j) {
        int idx = base + j;
        if (idx < nbkt) {
            int o = excl + v[j];
            offsets[idx] = o;
            cursor[idx]  = o;
        }
    }
}

// h = feat @ w^T. W in LDS fragment-contiguous: wfrag[(nt*8+ks)*64 + lane]
// -> every ds_read_b128 is lane-stride-1 16B (conflict-free). r8-proven.
__global__ __launch_bounds__(GEMM_THREADS) void gemm_kernel(
    const void* __restrict__ featp, const void* __restrict__ wp,
    unsigned short* __restrict__ hp, int n_nodes, int n_tiles,
    const int* __restrict__ flags)
{
    __shared__ short8 wfrag[4096];   // 64 KB
    const int f32mode = flags[0];

    for (int d = threadIdx.x; d < 4096; d += GEMM_THREADS) {
        const int nt   = d >> 9;
        const int ks   = (d >> 6) & 7;
        const int kg   = (d >> 4) & 3;
        const int mrow = d & 15;
        const int row  = nt * 16 + mrow;
        const int c    = row * 32 + ks * 4 + kg;   // 16B chunk index in W
        short8 v;
        if (!f32mode) {
            v = *(const short8*)((const char*)wp + (c << 4));
        } else {
            const float* f = (const float*)wp + c * 8;
            floatx4 v0 = *(const floatx4*)f;
            floatx4 v1 = *(const floatx4*)(f + 4);
#pragma unroll
            for (int j = 0; j < 4; ++j) {
                v[j]     = f32_to_bf16_bits(v0[j]);
                v[4 + j] = f32_to_bf16_bits(v1[j]);
            }
        }
        wfrag[d] = v;
    }
    __syncthreads();

    const int wid  = threadIdx.x >> 6;
    const int lane = threadIdx.x & 63;
    const int mrow = lane & 15;
    const int kg   = lane >> 4;

    auto loadA = [&](int tile, short8 (&a)[8]) {
        const int lrow = min(tile * 64 + wid * 16 + mrow, n_nodes - 1);
        if (!f32mode) {
            const short* fr = (const short*)featp + (size_t)lrow * F_IN;
#pragma unroll
            for (int ks = 0; ks < 8; ++ks)
                a[ks] = *(const short8*)(fr + ks * 32 + kg * 8);
        } else {
            const float* fr = (const float*)featp + (size_t)lrow * F_IN;
#pragma unroll
            for (int ks = 0; ks < 8; ++ks) {
                floatx4 v0 = *(const floatx4*)(fr + ks * 32 + kg * 8);
                floatx4 v1 = *(const floatx4*)(fr + ks * 32 + kg * 8 + 4);
                short8 t;
#pragma unroll
                for (int j = 0; j < 4; ++j) {
                    t[j]     = f32_to_bf16_bits(v0[j]);
                    t[4 + j] = f32_to_bf16_bits(v1[j]);
                }
                a[ks] = t;
            }
        }
    };

    auto compute = [&](int tile, short8 (&a)[8]) {
        floatx4 acc[8];
#pragma unroll
        for (int nt = 0; nt < 8; ++nt) acc[nt] = (floatx4){0.f, 0.f, 0.f, 0.f};
#pragma unroll
        for (int nt = 0; nt < 8; ++nt) {
#pragma unroll
            for (int ks = 0; ks < 8; ++ks) {
                const short8 b = wfrag[((nt * 8 + ks) << 6) + lane];
                acc[nt] = __builtin_amdgcn_mfma_f32_16x16x32_bf16(a[ks], b, acc[nt], 0, 0, 0);
            }
        }
        const int m0 = tile * 64 + wid * 16;
#pragma unroll
        for (int nt = 0; nt < 8; ++nt) {
            const int col = nt * 16 + mrow;
#pragma unroll
            for (int r = 0; r < 4; ++r) {
                const int orow = m0 + kg * 4 + r;
                if (orow < n_nodes)
                    hp[(size_t)orow * F_OUT + col] = (unsigned short)f32_to_bf16_bits(acc[nt][r]);
            }
        }
    };

    int tile = blockIdx.x;
    if (tile >= n_tiles) return;
    short8 a0[8], a1[8];
    loadA(tile, a0);
    bool cur0 = true;
    for (; tile < n_tiles; tile += gridDim.x) {
        const int nxt = tile + gridDim.x;
        if (cur0) {
            if (nxt < n_tiles) loadA(nxt, a1);
            compute(tile, a0);
        } else {
            if (nxt < n_tiles) loadA(nxt, a0);
            compute(tile, a1);
        }
        cur0 = !cur0;
    }
}

// Chunked binfill: per-block LDS hist -> one cursor atomic per (block,bucket)
// -> grouped writes of packed (src | localdst<<24). At nbkt=391 and 128
// blocks, runs average 32 entries = 128B -> full-line writes.
__global__ __launch_bounds__(FILL_THREADS) void binfill_kernel(
    const void* __restrict__ srcp, const void* __restrict__ dstp,
    int* __restrict__ cursor, unsigned* __restrict__ bucket_edges,
    int n_edges, int n_nodes, int nbkt, const int* __restrict__ flags)
{
    const int i64 = flags[1];
    __shared__ int hist[MAX_BKT];
    __shared__ int base[MAX_BKT];

    if (nbkt > MAX_BKT) {  // fallback: direct atomics
        const int stride = gridDim.x * blockDim.x;
        for (int e = blockIdx.x * blockDim.x + threadIdx.x; e < n_edges; e += stride) {
            int s, d;
            if (i64) { s = (int)((const long long*)srcp)[e]; d = (int)((const long long*)dstp)[e]; }
            else     { s = ((const int*)srcp)[e];            d = ((const int*)dstp)[e]; }
            if ((unsigned)d >= (unsigned)n_nodes) continue;
            if ((unsigned)s >= (unsigned)n_nodes) s = 0;
            int pos = atomicAdd(&cursor[d >> NODE_SHIFT], 1);
            bucket_edges[pos] = (unsigned)s | ((unsigned)(d & (BKT_NODES - 1)) << 24);
        }
        return;
    }

    const int chunk = (n_edges + gridDim.x - 1) / gridDim.x;
    const int e0 = blockIdx.x * chunk;
    const int e1 = min(e0 + chunk, n_edges);

    for (int j = threadIdx.x; j < nbkt; j += FILL_THREADS) hist[j] = 0;
    __syncthreads();
    for (int e = e0 + threadIdx.x; e < e1; e += FILL_THREADS) {
        int d = i64 ? (int)((const long long*)dstp)[e] : ((const int*)dstp)[e];
        if ((unsigned)d < (unsigned)n_nodes) atomicAdd(&hist[d >> NODE_SHIFT], 1);
    }
    __syncthreads();
    for (int j = threadIdx.x; j < nbkt; j += FILL_THREADS) {
        int c = hist[j];
        base[j] = c ? atomicAdd(&cursor[j], c) : 0;
    }
    __syncthreads();
    for (int j = threadIdx.x; j < nbkt; j += FILL_THREADS) hist[j] = 0;
    __syncthreads();
    for (int e = e0 + threadIdx.x; e < e1; e += FILL_THREADS) {
        int s, d;
        if (i64) { s = (int)((const long long*)srcp)[e]; d = (int)((const long long*)dstp)[e]; }
        else     { s = ((const int*)srcp)[e];            d = ((const int*)dstp)[e]; }
        if ((unsigned)d >= (unsigned)n_nodes) continue;
        if ((unsigned)s >= (unsigned)n_nodes) s = 0;
        const int b = d >> NODE_SHIFT;
        int pos = base[b] + atomicAdd(&hist[b], 1);
        bucket_edges[pos] = (unsigned)s | ((unsigned)(d & (BKT_NODES - 1)) << 24);
    }
}

// FOUR 512-thread blocks per coarse bucket: block (cb,q) filters the coarse
// bucket's edges for its 64-node quarter, counting-sorts into 16 KB LDS,
// then 8 waves consume nodes via work-steal. x4-wide 16B/lane gather,
// shfl_xor fold, fused mean+bias. Grid = 4*nbkt -> full occupancy.
__global__ __launch_bounds__(AGG_THREADS) void agg_kernel(
    const unsigned short* __restrict__ h, const unsigned* __restrict__ bucket_edges,
    const int* __restrict__ bucket_offsets, const int* __restrict__ bucket_counts,
    const void* __restrict__ biasp, void* __restrict__ outp,
    int n_nodes, int nbkt, const int* __restrict__ flags)
{
    __shared__ int s_src[AGG_CAP];        // 16 KB: quarter's src sorted by local dst
    __shared__ int hist[QTR_NODES];
    __shared__ int excl[QTR_NODES];
    __shared__ int cur2[QTR_NODES];
    __shared__ int node_cursor;
    __shared__ int qtotal;

    const int f32mode = flags[0];
    const int cb = blockIdx.x >> 2;
    const int q  = blockIdx.x & 3;
    if (cb >= nbkt) return;
    const int beg = bucket_offsets[cb];
    const int cnt = bucket_counts[cb];
    const int node0 = (cb << NODE_SHIFT) + q * QTR_NODES;
    if (node0 >= n_nodes) return;

    const int tid = threadIdx.x;
    const int wave = tid >> 6;
    const int lane = tid & 63;
    const int grp  = lane >> 4;   // edge slot 0..3
    const int sub  = lane & 15;   // col block: cols sub*8 .. sub*8+7

    float bs[8];
    if (f32mode) {
#pragma unroll
        for (int j = 0; j < 8; ++j) bs[j] = ((const float*)biasp)[sub * 8 + j];
    } else {
#pragma unroll
        for (int j = 0; j < 8; ++j)
            bs[j] = bf16bits_to_f32(((const unsigned short*)biasp)[sub * 8 + j]);
    }

    // ---- quarter histogram (also yields quarter total) ----
    if (tid < QTR_NODES) hist[tid] = 0;
    if (tid == 0) node_cursor = 0;
    __syncthreads();
    for (int i = tid; i < cnt; i += AGG_THREADS) {
        const int ld = bucket_edges[beg + i] >> 24;
        if ((ld >> 6) == q) atomicAdd(&hist[ld & (QTR_NODES - 1)], 1);
    }
    __syncthreads();
    if (tid == 0) {
        int run = 0;
#pragma unroll
        for (int j = 0; j < QTR_NODES; ++j) {
            excl[j] = run;
            cur2[j] = run;
            run += hist[j];
        }
        qtotal = run;
    }
    __syncthreads();

    if (qtotal > AGG_CAP) {
        // rare fallback: scan-filter per node (2-col per-lane layout)
        float bx, by;
        if (f32mode) {
            bx = ((const float*)biasp)[lane * 2];
            by = ((const float*)biasp)[lane * 2 + 1];
        } else {
            bx = bf16bits_to_f32(((const unsigned short*)biasp)[lane * 2]);
            by = bf16bits_to_f32(((const unsigned short*)biasp)[lane * 2 + 1]);
        }
        for (int nl = wave; nl < QTR_NODES; nl += AGG_THREADS / 64) {
            const int node = node0 + nl;
            if (node >= n_nodes) continue;
            const int want = q * QTR_NODES + nl;
            float ax = 0.f, ay = 0.f;
            int deg = 0;
            for (int i = 0; i < cnt; ++i) {
                const unsigned pk = bucket_edges[beg + i];
                if ((int)(pk >> 24) == want) {
                    const int s = (int)(pk & 0xFFFFFF);
                    unsigned p = *(const unsigned*)(h + (size_t)s * F_OUT + lane * 2);
                    ax += bf16bits_to_f32((unsigned short)p);
                    ay += bf16bits_to_f32((unsigned short)(p >> 16));
                    deg++;
                }
            }
            const float scale = 1.0f / fmaxf((float)deg, 1.0f);
            float ox = ax * scale + bx, oy = ay * scale + by;
            if (f32mode) {
                ((float*)outp)[(size_t)node * F_OUT + lane * 2]     = ox;
                ((float*)outp)[(size_t)node * F_OUT + lane * 2 + 1] = oy;
            } else {
                unsigned pkv = ((unsigned)(unsigned short)f32_to_bf16_bits(oy) << 16) |
                               (unsigned)(unsigned short)f32_to_bf16_bits(ox);
                ((unsigned*)outp)[(size_t)node * (F_OUT / 2) + lane] = pkv;
            }
        }
        return;
    }

    // ---- place this quarter's edges (counting sort) ----
    for (int i = tid; i < cnt; i += AGG_THREADS) {
        const unsigned pk = bucket_edges[beg + i];
        const int ld = pk >> 24;
        if ((ld >> 6) == q) {
            const int pos = atomicAdd(&cur2[ld & (QTR_NODES - 1)], 1);
            s_src[pos] = (int)(pk & 0xFFFFFF);
        }
    }
    __syncthreads();

    // ---- per-node accumulation, waves steal nodes from the LDS cursor ----
    for (;;) {
        int nl;
        if (lane == 0) nl = atomicAdd(&node_cursor, 1);
        nl = __shfl(nl, 0);
        if (nl >= QTR_NODES) break;
        const int node = node0 + nl;
        if (node >= n_nodes) continue;

        const int nbeg = excl[nl];
        const int ncnt = hist[nl];

        float acc[8];
#pragma unroll
        for (int j = 0; j < 8; ++j) acc[j] = 0.f;

        int i = 0;
        for (; i + 7 < ncnt; i += 8) {
            const int s0 = s_src[nbeg + i + grp];
            const int s1 = s_src[nbeg + i + 4 + grp];
            const short8 v0 = *(const short8*)(h + (size_t)s0 * F_OUT + sub * 8);
            const short8 v1 = *(const short8*)(h + (size_t)s1 * F_OUT + sub * 8);
#pragma unroll
            for (int j = 0; j < 8; ++j) {
                acc[j] += bf16bits_to_f32((unsigned short)v0[j]);
                acc[j] += bf16bits_to_f32((unsigned short)v1[j]);
            }
        }
        for (; i < ncnt; i += 4) {
            const int e = i + grp;
            if (e < ncnt) {
                const int s = s_src[nbeg + e];
                const short8 v = *(const short8*)(h + (size_t)s * F_OUT + sub * 8);
#pragma unroll
                for (int j = 0; j < 8; ++j)
                    acc[j] += bf16bits_to_f32((unsigned short)v[j]);
            }
        }

#pragma unroll
        for (int j = 0; j < 8; ++j) {
            acc[j] += __shfl_xor(acc[j], 16);
            acc[j] += __shfl_xor(acc[j], 32);
        }

        const float scale = 1.0f / fmaxf((float)ncnt, 1.0f);
        if (lane < 16) {
            if (f32mode) {
                float* o = (float*)outp + (size_t)node * F_OUT + sub * 8;
                floatx4 o0, o1;
#pragma unroll
                for (int j = 0; j < 4; ++j) {
                    o0[j] = acc[j] * scale + bs[j];
                    o1[j] = acc[4 + j] * scale + bs[4 + j];
                }
                *(floatx4*)o = o0;
                *(floatx4*)(o + 4) = o1;
            } else {
                short8 r;
#pragma unroll
                for (int j = 0; j < 8; ++j)
                    r[j] = f32_to_bf16_bits(acc[j] * scale + bs[j]);
                *(short8*)((unsigned short*)outp + (size_t)node * F_OUT + sub * 8) = r;
            }
        }
    }
}

extern "C" void kernel_launch(void* const* d_in, const int* in_sizes, int n_in,
                              void* d_out, int out_size, void* d_ws, size_t ws_size,
                              hipStream_t stream)
{
    const void* feat = d_in[0];
    const void* w    = d_in[1];
    const void* bias = d_in[2];
    const void* src  = d_in[3];
    const void* dst  = d_in[4];
    const int n_nodes = in_sizes[0] / F_IN;
    const int n_edges = in_sizes[3];
    const int nbkt = (n_nodes + BKT_NODES - 1) / BKT_NODES;  // 391 @ 100k

    char* ws = (char*)d_ws;
    auto align256 = [](size_t x) { return (x + 255) & ~(size_t)255; };

    size_t off = 0;
    int* flags = (int*)(ws + off);              off = align256(off + 256);
    int* bucket_counts = (int*)(ws + off);      off = align256(off + (size_t)nbkt * 4);
    int* bucket_offsets = (int*)(ws + off);     off = align256(off + (size_t)nbkt * 4);
    int* cursor = (int*)(ws + off);             off = align256(off + (size_t)nbkt * 4);
    unsigned* bucket_edges = (unsigned*)(ws + off);
    off = align256(off + (size_t)n_edges * 4);
    unsigned short* hp = (unsigned short*)(ws + off);
    off = align256(off + (size_t)n_nodes * F_OUT * 2);
    // total ~32 MB

    detect_kernel<<<1, 256, 0, stream>>>(feat, dst, flags, bucket_counts, nbkt);

    bincount_scan_kernel<<<512, 256, 0, stream>>>(dst, bucket_counts,
                                                  bucket_offsets, cursor,
                                                  n_edges, n_nodes, nbkt, flags);

    const int n_tiles = (n_nodes + 63) / 64;
    const int gemm_blocks = min(512, n_tiles);
    gemm_kernel<<<gemm_blocks, GEMM_THREADS, 0, stream>>>(
        feat, w, hp, n_nodes, n_tiles, flags);

    binfill_kernel<<<FILL_BLOCKS, FILL_THREADS, 0, stream>>>(
        src, dst, cursor, bucket_edges, n_edges, n_nodes, nbkt, flags);

    agg_kernel<<<nbkt * 4, AGG_THREADS, 0, stream>>>(
        hp, bucket_edges, bucket_offsets, bucket_counts, bias, d_out,
        n_nodes, nbkt, flags);
}

// Round 15
// 162.369 us; speedup vs baseline: 1.1674x; 1.1674x over previous
//
#include <hip/hip_runtime.h>
#include <hip/hip_bf16.h>

typedef __attribute__((ext_vector_type(8))) short short8;
typedef __attribute__((ext_vector_type(4))) float floatx4;

#define F_IN 256
#define F_OUT 128
#define NODE_SHIFT 8               // 256 nodes per bucket
#define BKT_NODES 256
#define MAX_BKT 2048
#define AGG_THREADS 512
#define AGG_CAP 6144               // max edges/bucket on LDS-sort path (mean 4096)
#define FILL_BLOCKS 128
#define FILL_THREADS 512
#define GEMM_THREADS 256

static __device__ __forceinline__ short f32_to_bf16_bits(float v) {
    __hip_bfloat16 t = __float2bfloat16(v);
    return *reinterpret_cast<short*>(&t);
}
static __device__ __forceinline__ float bf16bits_to_f32(unsigned short u) {
    unsigned x = (unsigned)u << 16;
    return __builtin_bit_cast(float, x);
}

// Deterministic input-dtype probe + zero bucket_counts + zero done-counter.
// flags[0]: 1 = floats are f32, 0 = bf16;  flags[1]: 1 = int64 idx, 0 = int32
// flags[8]: done-counter for the fused scan
__global__ __launch_bounds__(256) void detect_kernel(
    const void* __restrict__ featp, const void* __restrict__ dstp,
    int* __restrict__ flags, int* __restrict__ bucket_counts, int nbkt)
{
    for (int j = threadIdx.x; j < nbkt; j += 256) bucket_counts[j] = 0;
    if (threadIdx.x == 0) {
        const unsigned short* fb = (const unsigned short*)featp;
        int plaus = 0;
        for (int i = 0; i < 64; ++i) {
            unsigned short u = fb[2 * i];
            int ex = (u >> 7) & 0xFF;
            if (ex >= 118 && ex <= 137) plaus++;
        }
        flags[0] = (plaus >= 48) ? 0 : 1;

        const int* di = (const int*)dstp;
        int zeros = 0;
        for (int i = 0; i < 64; ++i)
            if (di[2 * i + 1] == 0) zeros++;
        flags[1] = (zeros >= 62) ? 1 : 0;
        flags[8] = 0;   // done counter
    }
}

// LDS-histogram of dst>>NODE_SHIFT, global merge; the LAST block to finish
// scans counts -> offsets+cursor (r9-proven handoff).
__global__ __launch_bounds__(256) void bincount_scan_kernel(
    const void* __restrict__ dstp, int* __restrict__ bucket_counts,
    int* __restrict__ offsets, int* __restrict__ cursor,
    int n_edges, int n_nodes, int nbkt, int* __restrict__ flags)
{
    const int i64 = flags[1];
    __shared__ int hist[MAX_BKT];
    __shared__ int is_last;
    const bool use_lds = (nbkt <= MAX_BKT);
    if (use_lds) {
        for (int j = threadIdx.x; j < nbkt; j += 256) hist[j] = 0;
        __syncthreads();
    }
    const int stride = gridDim.x * blockDim.x;
    for (int e = blockIdx.x * blockDim.x + threadIdx.x; e < n_edges; e += stride) {
        int d = i64 ? (int)((const long long*)dstp)[e] : ((const int*)dstp)[e];
        if ((unsigned)d >= (unsigned)n_nodes) continue;
        if (use_lds) atomicAdd(&hist[d >> NODE_SHIFT], 1);
        else         atomicAdd(&bucket_counts[d >> NODE_SHIFT], 1);
    }
    if (use_lds) {
        __syncthreads();
        for (int j = threadIdx.x; j < nbkt; j += 256) {
            int c = hist[j];
            if (c) atomicAdd(&bucket_counts[j], c);
        }
    }
    __threadfence();
    if (threadIdx.x == 0)
        is_last = (atomicAdd(&flags[8], 1) == (int)gridDim.x - 1);
    __syncthreads();
    if (!is_last) return;

    // exclusive scan (nbkt <= 4096), hist[] as scratch
    const int t = threadIdx.x;
    const int base = t * 16;
    int v[16];
    int run = 0;
#pragma unroll
    for (int j = 0; j < 16; ++j) {
        int idx = base + j;
        int x = (idx < nbkt)
            ? __hip_atomic_load(&bucket_counts[idx], __ATOMIC_RELAXED,
                                __HIP_MEMORY_SCOPE_AGENT)
            : 0;
        v[j] = run;
        run += x;
    }
    __syncthreads();
    hist[t] = run;
    __syncthreads();
    for (int off = 1; off < 256; off <<= 1) {
        int x = (t >= off) ? hist[t - off] : 0;
        __syncthreads();
        hist[t] += x;
        __syncthreads();
    }
    const int excl = hist[t] - run;
#pragma unroll
    for (int j = 0; j < 16; ++j) {
        int idx = base + j;
        if (idx < nbkt) {
            int o = excl + v[j];
            offsets[idx] = o;
            cursor[idx]  = o;
        }
    }
}

// h = feat @ w^T. W in LDS fragment-contiguous: wfrag[(nt*8+ks)*64 + lane]
// -> every ds_read_b128 is lane-stride-1 16B (conflict-free). r8-proven.
__global__ __launch_bounds__(GEMM_THREADS) void gemm_kernel(
    const void* __restrict__ featp, const void* __restrict__ wp,
    unsigned short* __restrict__ hp, int n_nodes, int n_tiles,
    const int* __restrict__ flags)
{
    __shared__ short8 wfrag[4096];   // 64 KB
    const int f32mode = flags[0];

    for (int d = threadIdx.x; d < 4096; d += GEMM_THREADS) {
        const int nt   = d >> 9;
        const int ks   = (d >> 6) & 7;
        const int kg   = (d >> 4) & 3;
        const int mrow = d & 15;
        const int row  = nt * 16 + mrow;
        const int c    = row * 32 + ks * 4 + kg;   // 16B chunk index in W
        short8 v;
        if (!f32mode) {
            v = *(const short8*)((const char*)wp + (c << 4));
        } else {
            const float* f = (const float*)wp + c * 8;
            floatx4 v0 = *(const floatx4*)f;
            floatx4 v1 = *(const floatx4*)(f + 4);
#pragma unroll
            for (int j = 0; j < 4; ++j) {
                v[j]     = f32_to_bf16_bits(v0[j]);
                v[4 + j] = f32_to_bf16_bits(v1[j]);
            }
        }
        wfrag[d] = v;
    }
    __syncthreads();

    const int wid  = threadIdx.x >> 6;
    const int lane = threadIdx.x & 63;
    const int mrow = lane & 15;
    const int kg   = lane >> 4;

    auto loadA = [&](int tile, short8 (&a)[8]) {
        const int lrow = min(tile * 64 + wid * 16 + mrow, n_nodes - 1);
        if (!f32mode) {
            const short* fr = (const short*)featp + (size_t)lrow * F_IN;
#pragma unroll
            for (int ks = 0; ks < 8; ++ks)
                a[ks] = *(const short8*)(fr + ks * 32 + kg * 8);
        } else {
            const float* fr = (const float*)featp + (size_t)lrow * F_IN;
#pragma unroll
            for (int ks = 0; ks < 8; ++ks) {
                floatx4 v0 = *(const floatx4*)(fr + ks * 32 + kg * 8);
                floatx4 v1 = *(const floatx4*)(fr + ks * 32 + kg * 8 + 4);
                short8 t;
#pragma unroll
                for (int j = 0; j < 4; ++j) {
                    t[j]     = f32_to_bf16_bits(v0[j]);
                    t[4 + j] = f32_to_bf16_bits(v1[j]);
                }
                a[ks] = t;
            }
        }
    };

    auto compute = [&](int tile, short8 (&a)[8]) {
        floatx4 acc[8];
#pragma unroll
        for (int nt = 0; nt < 8; ++nt) acc[nt] = (floatx4){0.f, 0.f, 0.f, 0.f};
#pragma unroll
        for (int nt = 0; nt < 8; ++nt) {
#pragma unroll
            for (int ks = 0; ks < 8; ++ks) {
                const short8 b = wfrag[((nt * 8 + ks) << 6) + lane];
                acc[nt] = __builtin_amdgcn_mfma_f32_16x16x32_bf16(a[ks], b, acc[nt], 0, 0, 0);
            }
        }
        const int m0 = tile * 64 + wid * 16;
#pragma unroll
        for (int nt = 0; nt < 8; ++nt) {
            const int col = nt * 16 + mrow;
#pragma unroll
            for (int r = 0; r < 4; ++r) {
                const int orow = m0 + kg * 4 + r;
                if (orow < n_nodes)
                    hp[(size_t)orow * F_OUT + col] = (unsigned short)f32_to_bf16_bits(acc[nt][r]);
            }
        }
    };

    int tile = blockIdx.x;
    if (tile >= n_tiles) return;
    short8 a0[8], a1[8];
    loadA(tile, a0);
    bool cur0 = true;
    for (; tile < n_tiles; tile += gridDim.x) {
        const int nxt = tile + gridDim.x;
        if (cur0) {
            if (nxt < n_tiles) loadA(nxt, a1);
            compute(tile, a0);
        } else {
            if (nxt < n_tiles) loadA(nxt, a0);
            compute(tile, a1);
        }
        cur0 = !cur0;
    }
}

// Chunked binfill: per-block LDS hist -> one cursor atomic per (block,bucket)
// -> grouped writes of packed (src | localdst<<24). At nbkt=391 and 128
// blocks, runs average 32 entries = 128B -> full-line writes.
__global__ __launch_bounds__(FILL_THREADS) void binfill_kernel(
    const void* __restrict__ srcp, const void* __restrict__ dstp,
    int* __restrict__ cursor, unsigned* __restrict__ bucket_edges,
    int n_edges, int n_nodes, int nbkt, const int* __restrict__ flags)
{
    const int i64 = flags[1];
    __shared__ int hist[MAX_BKT];
    __shared__ int base[MAX_BKT];

    if (nbkt > MAX_BKT) {  // fallback: direct atomics
        const int stride = gridDim.x * blockDim.x;
        for (int e = blockIdx.x * blockDim.x + threadIdx.x; e < n_edges; e += stride) {
            int s, d;
            if (i64) { s = (int)((const long long*)srcp)[e]; d = (int)((const long long*)dstp)[e]; }
            else     { s = ((const int*)srcp)[e];            d = ((const int*)dstp)[e]; }
            if ((unsigned)d >= (unsigned)n_nodes) continue;
            if ((unsigned)s >= (unsigned)n_nodes) s = 0;
            int pos = atomicAdd(&cursor[d >> NODE_SHIFT], 1);
            bucket_edges[pos] = (unsigned)s | ((unsigned)(d & (BKT_NODES - 1)) << 24);
        }
        return;
    }

    const int chunk = (n_edges + gridDim.x - 1) / gridDim.x;
    const int e0 = blockIdx.x * chunk;
    const int e1 = min(e0 + chunk, n_edges);

    for (int j = threadIdx.x; j < nbkt; j += FILL_THREADS) hist[j] = 0;
    __syncthreads();
    for (int e = e0 + threadIdx.x; e < e1; e += FILL_THREADS) {
        int d = i64 ? (int)((const long long*)dstp)[e] : ((const int*)dstp)[e];
        if ((unsigned)d < (unsigned)n_nodes) atomicAdd(&hist[d >> NODE_SHIFT], 1);
    }
    __syncthreads();
    for (int j = threadIdx.x; j < nbkt; j += FILL_THREADS) {
        int c = hist[j];
        base[j] = c ? atomicAdd(&cursor[j], c) : 0;
    }
    __syncthreads();
    for (int j = threadIdx.x; j < nbkt; j += FILL_THREADS) hist[j] = 0;
    __syncthreads();
    for (int e = e0 + threadIdx.x; e < e1; e += FILL_THREADS) {
        int s, d;
        if (i64) { s = (int)((const long long*)srcp)[e]; d = (int)((const long long*)dstp)[e]; }
        else     { s = ((const int*)srcp)[e];            d = ((const int*)dstp)[e]; }
        if ((unsigned)d >= (unsigned)n_nodes) continue;
        if ((unsigned)s >= (unsigned)n_nodes) s = 0;
        const int b = d >> NODE_SHIFT;
        int pos = base[b] + atomicAdd(&hist[b], 1);
        bucket_edges[pos] = (unsigned)s | ((unsigned)(d & (BKT_NODES - 1)) << 24);
    }
}

// One 512-thread block per 256-node bucket: counting-sort edges in LDS
// (256 bins, wave-parallel bin scan), then 8 waves consume nodes via an
// LDS work-steal cursor. x4-wide 16B/lane gather with 4 loads in flight,
// shfl_xor fold, fused mean+bias.
__global__ __launch_bounds__(AGG_THREADS) void agg_kernel(
    const unsigned short* __restrict__ h, const unsigned* __restrict__ bucket_edges,
    const int* __restrict__ bucket_offsets, const int* __restrict__ bucket_counts,
    const void* __restrict__ biasp, void* __restrict__ outp,
    int n_nodes, int nbkt, const int* __restrict__ flags)
{
    __shared__ int s_src[AGG_CAP];        // 24 KB: src sorted by local dst
    __shared__ int hist[BKT_NODES];       // 1 KB each
    __shared__ int excl[BKT_NODES];
    __shared__ int cur2[BKT_NODES];
    __shared__ int node_cursor;

    const int f32mode = flags[0];
    const int tid = threadIdx.x;
    const int wave = tid >> 6;
    const int lane = tid & 63;
    const int grp  = lane >> 4;   // edge slot 0..3
    const int sub  = lane & 15;   // col block: cols sub*8 .. sub*8+7

    float bs[8];
    if (f32mode) {
#pragma unroll
        for (int j = 0; j < 8; ++j) bs[j] = ((const float*)biasp)[sub * 8 + j];
    } else {
#pragma unroll
        for (int j = 0; j < 8; ++j)
            bs[j] = bf16bits_to_f32(((const unsigned short*)biasp)[sub * 8 + j]);
    }

    for (int bkt = blockIdx.x; bkt < nbkt; bkt += gridDim.x) {
        const int beg = bucket_offsets[bkt];
        const int cnt = bucket_counts[bkt];
        const int node0 = bkt << NODE_SHIFT;

        if (cnt > AGG_CAP) {
            // rare fallback: scan-filter per node (2-col per-lane layout)
            float bx, by;
            if (f32mode) {
                bx = ((const float*)biasp)[lane * 2];
                by = ((const float*)biasp)[lane * 2 + 1];
            } else {
                bx = bf16bits_to_f32(((const unsigned short*)biasp)[lane * 2]);
                by = bf16bits_to_f32(((const unsigned short*)biasp)[lane * 2 + 1]);
            }
            for (int nl = wave; nl < BKT_NODES; nl += AGG_THREADS / 64) {
                const int node = node0 + nl;
                if (node >= n_nodes) continue;
                float ax = 0.f, ay = 0.f;
                int deg = 0;
                for (int i = 0; i < cnt; ++i) {
                    const unsigned pk = bucket_edges[beg + i];
                    if ((int)(pk >> 24) == nl) {
                        const int s = (int)(pk & 0xFFFFFF);
                        unsigned p = *(const unsigned*)(h + (size_t)s * F_OUT + lane * 2);
                        ax += bf16bits_to_f32((unsigned short)p);
                        ay += bf16bits_to_f32((unsigned short)(p >> 16));
                        deg++;
                    }
                }
                const float scale = 1.0f / fmaxf((float)deg, 1.0f);
                float ox = ax * scale + bx, oy = ay * scale + by;
                if (f32mode) {
                    ((float*)outp)[(size_t)node * F_OUT + lane * 2]     = ox;
                    ((float*)outp)[(size_t)node * F_OUT + lane * 2 + 1] = oy;
                } else {
                    unsigned pkv = ((unsigned)(unsigned short)f32_to_bf16_bits(oy) << 16) |
                                   (unsigned)(unsigned short)f32_to_bf16_bits(ox);
                    ((unsigned*)outp)[(size_t)node * (F_OUT / 2) + lane] = pkv;
                }
            }
            continue;
        }

        __syncthreads();   // protect LDS from the previous iteration's readers

        // ---- LDS counting sort by local dst (256 bins) ----
        if (tid < BKT_NODES) hist[tid] = 0;
        if (tid == 0) node_cursor = 0;
        __syncthreads();
        for (int i = tid; i < cnt; i += AGG_THREADS)
            atomicAdd(&hist[bucket_edges[beg + i] >> 24], 1);
        __syncthreads();
        // wave-parallel exclusive bin scan (wave 0: 4 bins/lane + shfl_up)
        if (wave == 0) {
            const int b0 = lane * 4;
            const int h0 = hist[b0], h1 = hist[b0 + 1],
                      h2 = hist[b0 + 2], h3 = hist[b0 + 3];
            const int lsum = h0 + h1 + h2 + h3;
            int run = lsum;
#pragma unroll
            for (int off = 1; off < 64; off <<= 1) {
                int x = __shfl_up(run, off);
                if (lane >= off) run += x;
            }
            const int lexcl = run - lsum;
            excl[b0]     = lexcl;                cur2[b0]     = lexcl;
            excl[b0 + 1] = lexcl + h0;           cur2[b0 + 1] = lexcl + h0;
            excl[b0 + 2] = lexcl + h0 + h1;      cur2[b0 + 2] = lexcl + h0 + h1;
            excl[b0 + 3] = lexcl + h0 + h1 + h2; cur2[b0 + 3] = lexcl + h0 + h1 + h2;
        }
        __syncthreads();
        for (int i = tid; i < cnt; i += AGG_THREADS) {
            const unsigned pk = bucket_edges[beg + i];
            const int pos = atomicAdd(&cur2[pk >> 24], 1);
            s_src[pos] = (int)(pk & 0xFFFFFF);
        }
        __syncthreads();

        // ---- per-node accumulation, waves steal nodes from the LDS cursor ----
        for (;;) {
            int nl;
            if (lane == 0) nl = atomicAdd(&node_cursor, 1);
            nl = __shfl(nl, 0);
            if (nl >= BKT_NODES) break;
            const int node = node0 + nl;
            if (node >= n_nodes) continue;

            const int nbeg = excl[nl];
            const int ncnt = hist[nl];

            float acc[8];
#pragma unroll
            for (int j = 0; j < 8; ++j) acc[j] = 0.f;

            int i = 0;
            for (; i + 15 < ncnt; i += 16) {   // 16 edges/iter, 4 loads in flight
                const int s0 = s_src[nbeg + i + grp];
                const int s1 = s_src[nbeg + i + 4 + grp];
                const int s2 = s_src[nbeg + i + 8 + grp];
                const int s3 = s_src[nbeg + i + 12 + grp];
                const short8 v0 = *(const short8*)(h + (size_t)s0 * F_OUT + sub * 8);
                const short8 v1 = *(const short8*)(h + (size_t)s1 * F_OUT + sub * 8);
                const short8 v2 = *(const short8*)(h + (size_t)s2 * F_OUT + sub * 8);
                const short8 v3 = *(const short8*)(h + (size_t)s3 * F_OUT + sub * 8);
#pragma unroll
                for (int j = 0; j < 8; ++j) {
                    acc[j] += bf16bits_to_f32((unsigned short)v0[j]);
                    acc[j] += bf16bits_to_f32((unsigned short)v1[j]);
                    acc[j] += bf16bits_to_f32((unsigned short)v2[j]);
                    acc[j] += bf16bits_to_f32((unsigned short)v3[j]);
                }
            }
            for (; i + 7 < ncnt; i += 8) {     // 8 edges/iter, 2 loads
                const int s0 = s_src[nbeg + i + grp];
                const int s1 = s_src[nbeg + i + 4 + grp];
                const short8 v0 = *(const short8*)(h + (size_t)s0 * F_OUT + sub * 8);
                const short8 v1 = *(const short8*)(h + (size_t)s1 * F_OUT + sub * 8);
#pragma unroll
                for (int j = 0; j < 8; ++j) {
                    acc[j] += bf16bits_to_f32((unsigned short)v0[j]);
                    acc[j] += bf16bits_to_f32((unsigned short)v1[j]);
                }
            }
            for (; i < ncnt; i += 4) {          // predicated tail, 4 edges/iter
                const int e = i + grp;
                if (e < ncnt) {
                    const int s = s_src[nbeg + e];
                    const short8 v = *(const short8*)(h + (size_t)s * F_OUT + sub * 8);
#pragma unroll
                    for (int j = 0; j < 8; ++j)
                        acc[j] += bf16bits_to_f32((unsigned short)v[j]);
                }
            }

#pragma unroll
            for (int j = 0; j < 8; ++j) {
                acc[j] += __shfl_xor(acc[j], 16);
                acc[j] += __shfl_xor(acc[j], 32);
            }

            const float scale = 1.0f / fmaxf((float)ncnt, 1.0f);
            if (lane < 16) {
                if (f32mode) {
                    float* o = (float*)outp + (size_t)node * F_OUT + sub * 8;
                    floatx4 o0, o1;
#pragma unroll
                    for (int j = 0; j < 4; ++j) {
                        o0[j] = acc[j] * scale + bs[j];
                        o1[j] = acc[4 + j] * scale + bs[4 + j];
                    }
                    *(floatx4*)o = o0;
                    *(floatx4*)(o + 4) = o1;
                } else {
                    short8 r;
#pragma unroll
                    for (int j = 0; j < 8; ++j)
                        r[j] = f32_to_bf16_bits(acc[j] * scale + bs[j]);
                    *(short8*)((unsigned short*)outp + (size_t)node * F_OUT + sub * 8) = r;
                }
            }
        }
    }
}

extern "C" void kernel_launch(void* const* d_in, const int* in_sizes, int n_in,
                              void* d_out, int out_size, void* d_ws, size_t ws_size,
                              hipStream_t stream)
{
    const void* feat = d_in[0];
    const void* w    = d_in[1];
    const void* bias = d_in[2];
    const void* src  = d_in[3];
    const void* dst  = d_in[4];
    const int n_nodes = in_sizes[0] / F_IN;
    const int n_edges = in_sizes[3];
    const int nbkt = (n_nodes + BKT_NODES - 1) / BKT_NODES;  // 391 @ 100k

    char* ws = (char*)d_ws;
    auto align256 = [](size_t x) { return (x + 255) & ~(size_t)255; };

    size_t off = 0;
    int* flags = (int*)(ws + off);              off = align256(off + 256);
    int* bucket_counts = (int*)(ws + off);      off = align256(off + (size_t)nbkt * 4);
    int* bucket_offsets = (int*)(ws + off);     off = align256(off + (size_t)nbkt * 4);
    int* cursor = (int*)(ws + off);             off = align256(off + (size_t)nbkt * 4);
    unsigned* bucket_edges = (unsigned*)(ws + off);
    off = align256(off + (size_t)n_edges * 4);
    unsigned short* hp = (unsigned short*)(ws + off);
    off = align256(off + (size_t)n_nodes * F_OUT * 2);
    // total ~32 MB

    detect_kernel<<<1, 256, 0, stream>>>(feat, dst, flags, bucket_counts, nbkt);

    bincount_scan_kernel<<<256, 256, 0, stream>>>(dst, bucket_counts,
                                                  bucket_offsets, cursor,
                                                  n_edges, n_nodes, nbkt, flags);

    const int n_tiles = (n_nodes + 63) / 64;
    const int gemm_blocks = min(512, n_tiles);
    gemm_kernel<<<gemm_blocks, GEMM_THREADS, 0, stream>>>(
        feat, w, hp, n_nodes, n_tiles, flags);

    binfill_kernel<<<FILL_BLOCKS, FILL_THREADS, 0, stream>>>(
        src, dst, cursor, bucket_edges, n_edges, n_nodes, nbkt, flags);

    const int agg_blocks = min(1024, nbkt);
    agg_kernel<<<agg_blocks, AGG_THREADS, 0, stream>>>(
        hp, bucket_edges, bucket_offsets, bucket_counts, bias, d_out,
        n_nodes, nbkt, flags);
}

// Round 16
// 135.993 us; speedup vs baseline: 1.3938x; 1.1940x over previous
//
#include <hip/hip_runtime.h>
#include <hip/hip_bf16.h>

typedef __attribute__((ext_vector_type(8))) short short8;
typedef __attribute__((ext_vector_type(4))) float floatx4;

#define F_IN 256
#define F_OUT 128
#define NODE_SHIFT 8               // 256 nodes per bucket
#define BKT_NODES 256
#define MAX_BKT 2048
#define AGG_THREADS 512
#define AGG_CAP 6144               // max edges/bucket on LDS-sort path (mean 4096)
#define FILL_BLOCKS 128
#define FILL_THREADS 512
#define GEMM_THREADS 256

static __device__ __forceinline__ short f32_to_bf16_bits(float v) {
    __hip_bfloat16 t = __float2bfloat16(v);
    return *reinterpret_cast<short*>(&t);
}
static __device__ __forceinline__ float bf16bits_to_f32(unsigned short u) {
    unsigned x = (unsigned)u << 16;
    return __builtin_bit_cast(float, x);
}

// Deterministic input-dtype probe + zero the per-bucket cursors.
// flags[0]: 1 = floats are f32, 0 = bf16;  flags[1]: 1 = int64 idx, 0 = int32
__global__ __launch_bounds__(256) void detect_kernel(
    const void* __restrict__ featp, const void* __restrict__ dstp,
    int* __restrict__ flags, int* __restrict__ cursor, int nbkt)
{
    for (int j = threadIdx.x; j < nbkt; j += 256) cursor[j] = 0;
    if (threadIdx.x == 0) {
        const unsigned short* fb = (const unsigned short*)featp;
        int plaus = 0;
        for (int i = 0; i < 64; ++i) {
            unsigned short u = fb[2 * i];
            int ex = (u >> 7) & 0xFF;
            if (ex >= 118 && ex <= 137) plaus++;
        }
        flags[0] = (plaus >= 48) ? 0 : 1;

        const int* di = (const int*)dstp;
        int zeros = 0;
        for (int i = 0; i < 64; ++i)
            if (di[2 * i + 1] == 0) zeros++;
        flags[1] = (zeros >= 62) ? 1 : 0;
    }
}

// h = feat @ w^T. W in LDS fragment-contiguous: wfrag[(nt*8+ks)*64 + lane]
// -> every ds_read_b128 is lane-stride-1 16B (conflict-free). r8-proven.
__global__ __launch_bounds__(GEMM_THREADS) void gemm_kernel(
    const void* __restrict__ featp, const void* __restrict__ wp,
    unsigned short* __restrict__ hp, int n_nodes, int n_tiles,
    const int* __restrict__ flags)
{
    __shared__ short8 wfrag[4096];   // 64 KB
    const int f32mode = flags[0];

    for (int d = threadIdx.x; d < 4096; d += GEMM_THREADS) {
        const int nt   = d >> 9;
        const int ks   = (d >> 6) & 7;
        const int kg   = (d >> 4) & 3;
        const int mrow = d & 15;
        const int row  = nt * 16 + mrow;
        const int c    = row * 32 + ks * 4 + kg;   // 16B chunk index in W
        short8 v;
        if (!f32mode) {
            v = *(const short8*)((const char*)wp + (c << 4));
        } else {
            const float* f = (const float*)wp + c * 8;
            floatx4 v0 = *(const floatx4*)f;
            floatx4 v1 = *(const floatx4*)(f + 4);
#pragma unroll
            for (int j = 0; j < 4; ++j) {
                v[j]     = f32_to_bf16_bits(v0[j]);
                v[4 + j] = f32_to_bf16_bits(v1[j]);
            }
        }
        wfrag[d] = v;
    }
    __syncthreads();

    const int wid  = threadIdx.x >> 6;
    const int lane = threadIdx.x & 63;
    const int mrow = lane & 15;
    const int kg   = lane >> 4;

    auto loadA = [&](int tile, short8 (&a)[8]) {
        const int lrow = min(tile * 64 + wid * 16 + mrow, n_nodes - 1);
        if (!f32mode) {
            const short* fr = (const short*)featp + (size_t)lrow * F_IN;
#pragma unroll
            for (int ks = 0; ks < 8; ++ks)
                a[ks] = *(const short8*)(fr + ks * 32 + kg * 8);
        } else {
            const float* fr = (const float*)featp + (size_t)lrow * F_IN;
#pragma unroll
            for (int ks = 0; ks < 8; ++ks) {
                floatx4 v0 = *(const floatx4*)(fr + ks * 32 + kg * 8);
                floatx4 v1 = *(const floatx4*)(fr + ks * 32 + kg * 8 + 4);
                short8 t;
#pragma unroll
                for (int j = 0; j < 4; ++j) {
                    t[j]     = f32_to_bf16_bits(v0[j]);
                    t[4 + j] = f32_to_bf16_bits(v1[j]);
                }
                a[ks] = t;
            }
        }
    };

    auto compute = [&](int tile, short8 (&a)[8]) {
        floatx4 acc[8];
#pragma unroll
        for (int nt = 0; nt < 8; ++nt) acc[nt] = (floatx4){0.f, 0.f, 0.f, 0.f};
#pragma unroll
        for (int nt = 0; nt < 8; ++nt) {
#pragma unroll
            for (int ks = 0; ks < 8; ++ks) {
                const short8 b = wfrag[((nt * 8 + ks) << 6) + lane];
                acc[nt] = __builtin_amdgcn_mfma_f32_16x16x32_bf16(a[ks], b, acc[nt], 0, 0, 0);
            }
        }
        const int m0 = tile * 64 + wid * 16;
#pragma unroll
        for (int nt = 0; nt < 8; ++nt) {
            const int col = nt * 16 + mrow;
#pragma unroll
            for (int r = 0; r < 4; ++r) {
                const int orow = m0 + kg * 4 + r;
                if (orow < n_nodes)
                    hp[(size_t)orow * F_OUT + col] = (unsigned short)f32_to_bf16_bits(acc[nt][r]);
            }
        }
    };

    int tile = blockIdx.x;
    if (tile >= n_tiles) return;
    short8 a0[8], a1[8];
    loadA(tile, a0);
    bool cur0 = true;
    for (; tile < n_tiles; tile += gridDim.x) {
        const int nxt = tile + gridDim.x;
        if (cur0) {
            if (nxt < n_tiles) loadA(nxt, a1);
            compute(tile, a0);
        } else {
            if (nxt < n_tiles) loadA(nxt, a0);
            compute(tile, a1);
        }
        cur0 = !cur0;
    }
}

// Single-pass chunked binfill into FIXED-CAPACITY bucket regions
// (region bkt*cap, no count/scan prepass). Per-block LDS hist -> one cursor
// atomic per (block,bucket) -> grouped writes of packed (src | localdst<<24).
// Overflow (cursor > cap, adversarial-only) edges are simply not stored;
// agg detects cursor > cap and rescans raw src/dst for that bucket.
__global__ __launch_bounds__(FILL_THREADS) void binfill_kernel(
    const void* __restrict__ srcp, const void* __restrict__ dstp,
    int* __restrict__ cursor, unsigned* __restrict__ bucket_edges,
    int n_edges, int n_nodes, int nbkt, int cap, const int* __restrict__ flags)
{
    const int i64 = flags[1];
    __shared__ int hist[MAX_BKT];
    __shared__ int base[MAX_BKT];

    if (nbkt > MAX_BKT) {  // fallback: direct atomics
        const int stride = gridDim.x * blockDim.x;
        for (int e = blockIdx.x * blockDim.x + threadIdx.x; e < n_edges; e += stride) {
            int s, d;
            if (i64) { s = (int)((const long long*)srcp)[e]; d = (int)((const long long*)dstp)[e]; }
            else     { s = ((const int*)srcp)[e];            d = ((const int*)dstp)[e]; }
            if ((unsigned)d >= (unsigned)n_nodes) continue;
            if ((unsigned)s >= (unsigned)n_nodes) s = 0;
            const int b = d >> NODE_SHIFT;
            int pos = atomicAdd(&cursor[b], 1);
            if (pos < cap)
                bucket_edges[(size_t)b * cap + pos] =
                    (unsigned)s | ((unsigned)(d & (BKT_NODES - 1)) << 24);
        }
        return;
    }

    const int chunk = (n_edges + gridDim.x - 1) / gridDim.x;
    const int e0 = blockIdx.x * chunk;
    const int e1 = min(e0 + chunk, n_edges);

    for (int j = threadIdx.x; j < nbkt; j += FILL_THREADS) hist[j] = 0;
    __syncthreads();
    for (int e = e0 + threadIdx.x; e < e1; e += FILL_THREADS) {
        int d = i64 ? (int)((const long long*)dstp)[e] : ((const int*)dstp)[e];
        if ((unsigned)d < (unsigned)n_nodes) atomicAdd(&hist[d >> NODE_SHIFT], 1);
    }
    __syncthreads();
    for (int j = threadIdx.x; j < nbkt; j += FILL_THREADS) {
        int c = hist[j];
        base[j] = c ? atomicAdd(&cursor[j], c) : 0;
    }
    __syncthreads();
    for (int j = threadIdx.x; j < nbkt; j += FILL_THREADS) hist[j] = 0;
    __syncthreads();
    for (int e = e0 + threadIdx.x; e < e1; e += FILL_THREADS) {
        int s, d;
        if (i64) { s = (int)((const long long*)srcp)[e]; d = (int)((const long long*)dstp)[e]; }
        else     { s = ((const int*)srcp)[e];            d = ((const int*)dstp)[e]; }
        if ((unsigned)d >= (unsigned)n_nodes) continue;
        if ((unsigned)s >= (unsigned)n_nodes) s = 0;
        const int b = d >> NODE_SHIFT;
        const int pos = base[b] + atomicAdd(&hist[b], 1);
        if (pos < cap)
            bucket_edges[(size_t)b * cap + pos] =
                (unsigned)s | ((unsigned)(d & (BKT_NODES - 1)) << 24);
    }
}

// One 512-thread block per 256-node bucket (region = bkt*cap, count = cursor):
// counting-sort edges in LDS (256 bins, wave-parallel bin scan), then 8 waves
// consume nodes via an LDS work-steal cursor. x4-wide 16B/lane gather with
// 4 loads in flight, shfl_xor fold, fused mean+bias.
// Tier 2 (AGG_CAP<cnt<=cap): scan-filter the region. Tier 3 (cnt>cap,
// adversarial-only): rescan raw src/dst.
__global__ __launch_bounds__(AGG_THREADS) void agg_kernel(
    const unsigned short* __restrict__ h, const unsigned* __restrict__ bucket_edges,
    const int* __restrict__ cursor, const void* __restrict__ srcp,
    const void* __restrict__ dstp, int n_edges,
    const void* __restrict__ biasp, void* __restrict__ outp,
    int n_nodes, int nbkt, int cap, const int* __restrict__ flags)
{
    __shared__ int s_src[AGG_CAP];        // 24 KB: src sorted by local dst
    __shared__ int hist[BKT_NODES];       // 1 KB each
    __shared__ int excl[BKT_NODES];
    __shared__ int cur2[BKT_NODES];
    __shared__ int node_cursor;

    const int f32mode = flags[0];
    const int i64 = flags[1];
    const int tid = threadIdx.x;
    const int wave = tid >> 6;
    const int lane = tid & 63;
    const int grp  = lane >> 4;   // edge slot 0..3
    const int sub  = lane & 15;   // col block: cols sub*8 .. sub*8+7

    float bs[8];
    if (f32mode) {
#pragma unroll
        for (int j = 0; j < 8; ++j) bs[j] = ((const float*)biasp)[sub * 8 + j];
    } else {
#pragma unroll
        for (int j = 0; j < 8; ++j)
            bs[j] = bf16bits_to_f32(((const unsigned short*)biasp)[sub * 8 + j]);
    }

    for (int bkt = blockIdx.x; bkt < nbkt; bkt += gridDim.x) {
        const size_t beg = (size_t)bkt * cap;
        const int cnt = cursor[bkt];
        const int node0 = bkt << NODE_SHIFT;

        if (cnt > cap) {
            // adversarial-only: region incomplete -> rescan raw src/dst
            float bx, by;
            if (f32mode) {
                bx = ((const float*)biasp)[lane * 2];
                by = ((const float*)biasp)[lane * 2 + 1];
            } else {
                bx = bf16bits_to_f32(((const unsigned short*)biasp)[lane * 2]);
                by = bf16bits_to_f32(((const unsigned short*)biasp)[lane * 2 + 1]);
            }
            for (int nl = wave; nl < BKT_NODES; nl += AGG_THREADS / 64) {
                const int node = node0 + nl;
                if (node >= n_nodes) continue;
                float ax = 0.f, ay = 0.f;
                int deg = 0;
                for (int e = 0; e < n_edges; ++e) {
                    int d = i64 ? (int)((const long long*)dstp)[e]
                                : ((const int*)dstp)[e];
                    if (d == node) {
                        int s = i64 ? (int)((const long long*)srcp)[e]
                                    : ((const int*)srcp)[e];
                        if ((unsigned)s >= (unsigned)n_nodes) s = 0;
                        unsigned p = *(const unsigned*)(h + (size_t)s * F_OUT + lane * 2);
                        ax += bf16bits_to_f32((unsigned short)p);
                        ay += bf16bits_to_f32((unsigned short)(p >> 16));
                        deg++;
                    }
                }
                const float scale = 1.0f / fmaxf((float)deg, 1.0f);
                float ox = ax * scale + bx, oy = ay * scale + by;
                if (f32mode) {
                    ((float*)outp)[(size_t)node * F_OUT + lane * 2]     = ox;
                    ((float*)outp)[(size_t)node * F_OUT + lane * 2 + 1] = oy;
                } else {
                    unsigned pkv = ((unsigned)(unsigned short)f32_to_bf16_bits(oy) << 16) |
                                   (unsigned)(unsigned short)f32_to_bf16_bits(ox);
                    ((unsigned*)outp)[(size_t)node * (F_OUT / 2) + lane] = pkv;
                }
            }
            continue;
        }

        if (cnt > AGG_CAP) {
            // scan-filter the region per node (2-col per-lane layout)
            float bx, by;
            if (f32mode) {
                bx = ((const float*)biasp)[lane * 2];
                by = ((const float*)biasp)[lane * 2 + 1];
            } else {
                bx = bf16bits_to_f32(((const unsigned short*)biasp)[lane * 2]);
                by = bf16bits_to_f32(((const unsigned short*)biasp)[lane * 2 + 1]);
            }
            for (int nl = wave; nl < BKT_NODES; nl += AGG_THREADS / 64) {
                const int node = node0 + nl;
                if (node >= n_nodes) continue;
                float ax = 0.f, ay = 0.f;
                int deg = 0;
                for (int i = 0; i < cnt; ++i) {
                    const unsigned pk = bucket_edges[beg + i];
                    if ((int)(pk >> 24) == nl) {
                        const int s = (int)(pk & 0xFFFFFF);
                        unsigned p = *(const unsigned*)(h + (size_t)s * F_OUT + lane * 2);
                        ax += bf16bits_to_f32((unsigned short)p);
                        ay += bf16bits_to_f32((unsigned short)(p >> 16));
                        deg++;
                    }
                }
                const float scale = 1.0f / fmaxf((float)deg, 1.0f);
                float ox = ax * scale + bx, oy = ay * scale + by;
                if (f32mode) {
                    ((float*)outp)[(size_t)node * F_OUT + lane * 2]     = ox;
                    ((float*)outp)[(size_t)node * F_OUT + lane * 2 + 1] = oy;
                } else {
                    unsigned pkv = ((unsigned)(unsigned short)f32_to_bf16_bits(oy) << 16) |
                                   (unsigned)(unsigned short)f32_to_bf16_bits(ox);
                    ((unsigned*)outp)[(size_t)node * (F_OUT / 2) + lane] = pkv;
                }
            }
            continue;
        }

        __syncthreads();   // protect LDS from the previous iteration's readers

        // ---- LDS counting sort by local dst (256 bins) ----
        if (tid < BKT_NODES) hist[tid] = 0;
        if (tid == 0) node_cursor = 0;
        __syncthreads();
        for (int i = tid; i < cnt; i += AGG_THREADS)
            atomicAdd(&hist[bucket_edges[beg + i] >> 24], 1);
        __syncthreads();
        // wave-parallel exclusive bin scan (wave 0: 4 bins/lane + shfl_up)
        if (wave == 0) {
            const int b0 = lane * 4;
            const int h0 = hist[b0], h1 = hist[b0 + 1],
                      h2 = hist[b0 + 2], h3 = hist[b0 + 3];
            const int lsum = h0 + h1 + h2 + h3;
            int run = lsum;
#pragma unroll
            for (int off = 1; off < 64; off <<= 1) {
                int x = __shfl_up(run, off);
                if (lane >= off) run += x;
            }
            const int lexcl = run - lsum;
            excl[b0]     = lexcl;                cur2[b0]     = lexcl;
            excl[b0 + 1] = lexcl + h0;           cur2[b0 + 1] = lexcl + h0;
            excl[b0 + 2] = lexcl + h0 + h1;      cur2[b0 + 2] = lexcl + h0 + h1;
            excl[b0 + 3] = lexcl + h0 + h1 + h2; cur2[b0 + 3] = lexcl + h0 + h1 + h2;
        }
        __syncthreads();
        for (int i = tid; i < cnt; i += AGG_THREADS) {
            const unsigned pk = bucket_edges[beg + i];
            const int pos = atomicAdd(&cur2[pk >> 24], 1);
            s_src[pos] = (int)(pk & 0xFFFFFF);
        }
        __syncthreads();

        // ---- per-node accumulation, waves steal nodes from the LDS cursor ----
        for (;;) {
            int nl;
            if (lane == 0) nl = atomicAdd(&node_cursor, 1);
            nl = __shfl(nl, 0);
            if (nl >= BKT_NODES) break;
            const int node = node0 + nl;
            if (node >= n_nodes) continue;

            const int nbeg = excl[nl];
            const int ncnt = hist[nl];

            float acc[8];
#pragma unroll
            for (int j = 0; j < 8; ++j) acc[j] = 0.f;

            int i = 0;
            for (; i + 15 < ncnt; i += 16) {   // 16 edges/iter, 4 loads in flight
                const int s0 = s_src[nbeg + i + grp];
                const int s1 = s_src[nbeg + i + 4 + grp];
                const int s2 = s_src[nbeg + i + 8 + grp];
                const int s3 = s_src[nbeg + i + 12 + grp];
                const short8 v0 = *(const short8*)(h + (size_t)s0 * F_OUT + sub * 8);
                const short8 v1 = *(const short8*)(h + (size_t)s1 * F_OUT + sub * 8);
                const short8 v2 = *(const short8*)(h + (size_t)s2 * F_OUT + sub * 8);
                const short8 v3 = *(const short8*)(h + (size_t)s3 * F_OUT + sub * 8);
#pragma unroll
                for (int j = 0; j < 8; ++j) {
                    acc[j] += bf16bits_to_f32((unsigned short)v0[j]);
                    acc[j] += bf16bits_to_f32((unsigned short)v1[j]);
                    acc[j] += bf16bits_to_f32((unsigned short)v2[j]);
                    acc[j] += bf16bits_to_f32((unsigned short)v3[j]);
                }
            }
            for (; i + 7 < ncnt; i += 8) {     // 8 edges/iter, 2 loads
                const int s0 = s_src[nbeg + i + grp];
                const int s1 = s_src[nbeg + i + 4 + grp];
                const short8 v0 = *(const short8*)(h + (size_t)s0 * F_OUT + sub * 8);
                const short8 v1 = *(const short8*)(h + (size_t)s1 * F_OUT + sub * 8);
#pragma unroll
                for (int j = 0; j < 8; ++j) {
                    acc[j] += bf16bits_to_f32((unsigned short)v0[j]);
                    acc[j] += bf16bits_to_f32((unsigned short)v1[j]);
                }
            }
            for (; i < ncnt; i += 4) {          // predicated tail, 4 edges/iter
                const int e = i + grp;
                if (e < ncnt) {
                    const int s = s_src[nbeg + e];
                    const short8 v = *(const short8*)(h + (size_t)s * F_OUT + sub * 8);
#pragma unroll
                    for (int j = 0; j < 8; ++j)
                        acc[j] += bf16bits_to_f32((unsigned short)v[j]);
                }
            }

#pragma unroll
            for (int j = 0; j < 8; ++j) {
                acc[j] += __shfl_xor(acc[j], 16);
                acc[j] += __shfl_xor(acc[j], 32);
            }

            const float scale = 1.0f / fmaxf((float)ncnt, 1.0f);
            if (lane < 16) {
                if (f32mode) {
                    float* o = (float*)outp + (size_t)node * F_OUT + sub * 8;
                    floatx4 o0, o1;
#pragma unroll
                    for (int j = 0; j < 4; ++j) {
                        o0[j] = acc[j] * scale + bs[j];
                        o1[j] = acc[4 + j] * scale + bs[4 + j];
                    }
                    *(floatx4*)o = o0;
                    *(floatx4*)(o + 4) = o1;
                } else {
                    short8 r;
#pragma unroll
                    for (int j = 0; j < 8; ++j)
                        r[j] = f32_to_bf16_bits(acc[j] * scale + bs[j]);
                    *(short8*)((unsigned short*)outp + (size_t)node * F_OUT + sub * 8) = r;
                }
            }
        }
    }
}

extern "C" void kernel_launch(void* const* d_in, const int* in_sizes, int n_in,
                              void* d_out, int out_size, void* d_ws, size_t ws_size,
                              hipStream_t stream)
{
    const void* feat = d_in[0];
    const void* w    = d_in[1];
    const void* bias = d_in[2];
    const void* src  = d_in[3];
    const void* dst  = d_in[4];
    const int n_nodes = in_sizes[0] / F_IN;
    const int n_edges = in_sizes[3];
    const int nbkt = (n_nodes + BKT_NODES - 1) / BKT_NODES;  // 391 @ 100k

    // fixed per-bucket capacity ~ 2x mean, rounded up to 1024
    int cap = (int)((2LL * n_edges / nbkt + 1023) / 1024) * 1024;
    if (cap < 2048) cap = 2048;

    char* ws = (char*)d_ws;
    auto align256 = [](size_t x) { return (x + 255) & ~(size_t)255; };

    size_t off = 0;
    int* flags = (int*)(ws + off);              off = align256(off + 256);
    int* cursor = (int*)(ws + off);             off = align256(off + (size_t)nbkt * 4);
    unsigned* bucket_edges = (unsigned*)(ws + off);
    off = align256(off + (size_t)nbkt * cap * 4);
    unsigned short* hp = (unsigned short*)(ws + off);
    off = align256(off + (size_t)n_nodes * F_OUT * 2);
    // total ~38.6 MB @ 100k/1.6M

    detect_kernel<<<1, 256, 0, stream>>>(feat, dst, flags, cursor, nbkt);

    const int n_tiles = (n_nodes + 63) / 64;
    const int gemm_blocks = min(512, n_tiles);
    gemm_kernel<<<gemm_blocks, GEMM_THREADS, 0, stream>>>(
        feat, w, hp, n_nodes, n_tiles, flags);

    binfill_kernel<<<FILL_BLOCKS, FILL_THREADS, 0, stream>>>(
        src, dst, cursor, bucket_edges, n_edges, n_nodes, nbkt, cap, flags);

    const int agg_blocks = min(1024, nbkt);
    agg_kernel<<<agg_blocks, AGG_THREADS, 0, stream>>>(
        hp, bucket_edges, cursor, src, dst, n_edges, bias, d_out,
        n_nodes, nbkt, cap, flags);
}

// Round 17
// 135.878 us; speedup vs baseline: 1.3950x; 1.0008x over previous
//
#include <hip/hip_runtime.h>
#include <hip/hip_bf16.h>

typedef __attribute__((ext_vector_type(8))) short short8;
typedef __attribute__((ext_vector_type(4))) float floatx4;

#define F_IN 256
#define F_OUT 128
#define NODE_SHIFT 8               // 256 nodes per bucket
#define BKT_NODES 256
#define MAX_BKT 2048
#define AGG_THREADS 512
#define AGG_CAP 6144               // max edges/bucket on LDS-sort path (mean 4096)
#define FILL_BLOCKS 128
#define FILL_THREADS 512
#define GEMM_THREADS 256

static __device__ __forceinline__ short f32_to_bf16_bits(float v) {
    __hip_bfloat16 t = __float2bfloat16(v);
    return *reinterpret_cast<short*>(&t);
}
static __device__ __forceinline__ float bf16bits_to_f32(unsigned short u) {
    unsigned x = (unsigned)u << 16;
    return __builtin_bit_cast(float, x);
}

// Deterministic inline dtype probes (identical result in every block).
// f32 probe: bf16-view of f32 data has junk exponents at even indices.
static __device__ __forceinline__ int probe_f32(const void* featp) {
    const unsigned short* fb = (const unsigned short*)featp;
    int plaus = 0;
    for (int i = 0; i < 64; ++i) {
        int ex = (fb[2 * i] >> 7) & 0xFF;
        if (ex >= 118 && ex <= 137) plaus++;
    }
    return (plaus >= 48) ? 0 : 1;
}
// i64 probe: int64 indices < 2^31 have zero high words.
static __device__ __forceinline__ int probe_i64(const void* dstp) {
    const int* di = (const int*)dstp;
    int zeros = 0;
    for (int i = 0; i < 64; ++i)
        if (di[2 * i + 1] == 0) zeros++;
    return (zeros >= 62) ? 1 : 0;
}

// h = feat @ w^T. W in LDS fragment-contiguous: wfrag[(nt*8+ks)*64 + lane]
// -> every ds_read_b128 is lane-stride-1 16B (conflict-free). r8-proven.
// Also zeroes the binfill cursor (idempotent across blocks; stream order
// guarantees completion before binfill).
__global__ __launch_bounds__(GEMM_THREADS) void gemm_kernel(
    const void* __restrict__ featp, const void* __restrict__ wp,
    unsigned short* __restrict__ hp, int n_nodes, int n_tiles,
    int* __restrict__ cursor, int nbkt)
{
    __shared__ short8 wfrag[4096];   // 64 KB
    __shared__ int sh_f32;

    for (int j = threadIdx.x; j < nbkt; j += GEMM_THREADS) cursor[j] = 0;
    if (threadIdx.x == 0) sh_f32 = probe_f32(featp);
    __syncthreads();
    const int f32mode = sh_f32;

    for (int d = threadIdx.x; d < 4096; d += GEMM_THREADS) {
        const int nt   = d >> 9;
        const int ks   = (d >> 6) & 7;
        const int kg   = (d >> 4) & 3;
        const int mrow = d & 15;
        const int row  = nt * 16 + mrow;
        const int c    = row * 32 + ks * 4 + kg;   // 16B chunk index in W
        short8 v;
        if (!f32mode) {
            v = *(const short8*)((const char*)wp + (c << 4));
        } else {
            const float* f = (const float*)wp + c * 8;
            floatx4 v0 = *(const floatx4*)f;
            floatx4 v1 = *(const floatx4*)(f + 4);
#pragma unroll
            for (int j = 0; j < 4; ++j) {
                v[j]     = f32_to_bf16_bits(v0[j]);
                v[4 + j] = f32_to_bf16_bits(v1[j]);
            }
        }
        wfrag[d] = v;
    }
    __syncthreads();

    const int wid  = threadIdx.x >> 6;
    const int lane = threadIdx.x & 63;
    const int mrow = lane & 15;
    const int kg   = lane >> 4;

    auto loadA = [&](int tile, short8 (&a)[8]) {
        const int lrow = min(tile * 64 + wid * 16 + mrow, n_nodes - 1);
        if (!f32mode) {
            const short* fr = (const short*)featp + (size_t)lrow * F_IN;
#pragma unroll
            for (int ks = 0; ks < 8; ++ks)
                a[ks] = *(const short8*)(fr + ks * 32 + kg * 8);
        } else {
            const float* fr = (const float*)featp + (size_t)lrow * F_IN;
#pragma unroll
            for (int ks = 0; ks < 8; ++ks) {
                floatx4 v0 = *(const floatx4*)(fr + ks * 32 + kg * 8);
                floatx4 v1 = *(const floatx4*)(fr + ks * 32 + kg * 8 + 4);
                short8 t;
#pragma unroll
                for (int j = 0; j < 4; ++j) {
                    t[j]     = f32_to_bf16_bits(v0[j]);
                    t[4 + j] = f32_to_bf16_bits(v1[j]);
                }
                a[ks] = t;
            }
        }
    };

    auto compute = [&](int tile, short8 (&a)[8]) {
        floatx4 acc[8];
#pragma unroll
        for (int nt = 0; nt < 8; ++nt) acc[nt] = (floatx4){0.f, 0.f, 0.f, 0.f};
#pragma unroll
        for (int nt = 0; nt < 8; ++nt) {
#pragma unroll
            for (int ks = 0; ks < 8; ++ks) {
                const short8 b = wfrag[((nt * 8 + ks) << 6) + lane];
                acc[nt] = __builtin_amdgcn_mfma_f32_16x16x32_bf16(a[ks], b, acc[nt], 0, 0, 0);
            }
        }
        const int m0 = tile * 64 + wid * 16;
#pragma unroll
        for (int nt = 0; nt < 8; ++nt) {
            const int col = nt * 16 + mrow;
#pragma unroll
            for (int r = 0; r < 4; ++r) {
                const int orow = m0 + kg * 4 + r;
                if (orow < n_nodes)
                    hp[(size_t)orow * F_OUT + col] = (unsigned short)f32_to_bf16_bits(acc[nt][r]);
            }
        }
    };

    int tile = blockIdx.x;
    if (tile >= n_tiles) return;
    short8 a0[8], a1[8];
    loadA(tile, a0);
    bool cur0 = true;
    for (; tile < n_tiles; tile += gridDim.x) {
        const int nxt = tile + gridDim.x;
        if (cur0) {
            if (nxt < n_tiles) loadA(nxt, a1);
            compute(tile, a0);
        } else {
            if (nxt < n_tiles) loadA(nxt, a0);
            compute(tile, a1);
        }
        cur0 = !cur0;
    }
}

// Single-pass chunked binfill into FIXED-CAPACITY bucket regions
// (region bkt*cap, no count/scan prepass). Per-block LDS hist -> one cursor
// atomic per (block,bucket) -> grouped writes of packed (src | localdst<<24).
// Overflow (cursor > cap, adversarial-only) edges are simply not stored;
// agg detects cursor > cap and rescans raw src/dst for that bucket.
__global__ __launch_bounds__(FILL_THREADS) void binfill_kernel(
    const void* __restrict__ srcp, const void* __restrict__ dstp,
    int* __restrict__ cursor, unsigned* __restrict__ bucket_edges,
    int n_edges, int n_nodes, int nbkt, int cap)
{
    __shared__ int hist[MAX_BKT];
    __shared__ int base[MAX_BKT];
    __shared__ int sh_i64;

    if (threadIdx.x == 0) sh_i64 = probe_i64(dstp);
    __syncthreads();
    const int i64 = sh_i64;

    if (nbkt > MAX_BKT) {  // fallback: direct atomics
        const int stride = gridDim.x * blockDim.x;
        for (int e = blockIdx.x * blockDim.x + threadIdx.x; e < n_edges; e += stride) {
            int s, d;
            if (i64) { s = (int)((const long long*)srcp)[e]; d = (int)((const long long*)dstp)[e]; }
            else     { s = ((const int*)srcp)[e];            d = ((const int*)dstp)[e]; }
            if ((unsigned)d >= (unsigned)n_nodes) continue;
            if ((unsigned)s >= (unsigned)n_nodes) s = 0;
            const int b = d >> NODE_SHIFT;
            int pos = atomicAdd(&cursor[b], 1);
            if (pos < cap)
                bucket_edges[(size_t)b * cap + pos] =
                    (unsigned)s | ((unsigned)(d & (BKT_NODES - 1)) << 24);
        }
        return;
    }

    const int chunk = (n_edges + gridDim.x - 1) / gridDim.x;
    const int e0 = blockIdx.x * chunk;
    const int e1 = min(e0 + chunk, n_edges);

    for (int j = threadIdx.x; j < nbkt; j += FILL_THREADS) hist[j] = 0;
    __syncthreads();
    for (int e = e0 + threadIdx.x; e < e1; e += FILL_THREADS) {
        int d = i64 ? (int)((const long long*)dstp)[e] : ((const int*)dstp)[e];
        if ((unsigned)d < (unsigned)n_nodes) atomicAdd(&hist[d >> NODE_SHIFT], 1);
    }
    __syncthreads();
    for (int j = threadIdx.x; j < nbkt; j += FILL_THREADS) {
        int c = hist[j];
        base[j] = c ? atomicAdd(&cursor[j], c) : 0;
    }
    __syncthreads();
    for (int j = threadIdx.x; j < nbkt; j += FILL_THREADS) hist[j] = 0;
    __syncthreads();
    for (int e = e0 + threadIdx.x; e < e1; e += FILL_THREADS) {
        int s, d;
        if (i64) { s = (int)((const long long*)srcp)[e]; d = (int)((const long long*)dstp)[e]; }
        else     { s = ((const int*)srcp)[e];            d = ((const int*)dstp)[e]; }
        if ((unsigned)d >= (unsigned)n_nodes) continue;
        if ((unsigned)s >= (unsigned)n_nodes) s = 0;
        const int b = d >> NODE_SHIFT;
        const int pos = base[b] + atomicAdd(&hist[b], 1);
        if (pos < cap)
            bucket_edges[(size_t)b * cap + pos] =
                (unsigned)s | ((unsigned)(d & (BKT_NODES - 1)) << 24);
    }
}

// One 512-thread block per 256-node bucket (region = bkt*cap, count = cursor):
// counting-sort edges in LDS (256 bins, wave-parallel bin scan), then 8 waves
// consume nodes via an LDS work-steal cursor. x4-wide 16B/lane gather with
// 4 loads in flight, shfl_xor fold, fused mean+bias.
// Tier 2 (AGG_CAP<cnt<=cap): scan-filter the region. Tier 3 (cnt>cap,
// adversarial-only): rescan raw src/dst.
__global__ __launch_bounds__(AGG_THREADS) void agg_kernel(
    const unsigned short* __restrict__ h, const unsigned* __restrict__ bucket_edges,
    const int* __restrict__ cursor, const void* __restrict__ srcp,
    const void* __restrict__ dstp, int n_edges,
    const void* __restrict__ biasp, void* __restrict__ outp,
    int n_nodes, int nbkt, int cap, const void* __restrict__ featp)
{
    __shared__ int s_src[AGG_CAP];        // 24 KB: src sorted by local dst
    __shared__ int hist[BKT_NODES];       // 1 KB each
    __shared__ int excl[BKT_NODES];
    __shared__ int cur2[BKT_NODES];
    __shared__ int node_cursor;
    __shared__ int sh_flags2[2];

    if (threadIdx.x == 0) {
        sh_flags2[0] = probe_f32(featp);
        sh_flags2[1] = probe_i64(dstp);
    }
    __syncthreads();
    const int f32mode = sh_flags2[0];
    const int i64 = sh_flags2[1];

    const int tid = threadIdx.x;
    const int wave = tid >> 6;
    const int lane = tid & 63;
    const int grp  = lane >> 4;   // edge slot 0..3
    const int sub  = lane & 15;   // col block: cols sub*8 .. sub*8+7

    float bs[8];
    if (f32mode) {
#pragma unroll
        for (int j = 0; j < 8; ++j) bs[j] = ((const float*)biasp)[sub * 8 + j];
    } else {
#pragma unroll
        for (int j = 0; j < 8; ++j)
            bs[j] = bf16bits_to_f32(((const unsigned short*)biasp)[sub * 8 + j]);
    }

    for (int bkt = blockIdx.x; bkt < nbkt; bkt += gridDim.x) {
        const size_t beg = (size_t)bkt * cap;
        const int cnt = cursor[bkt];
        const int node0 = bkt << NODE_SHIFT;

        if (cnt > cap) {
            // adversarial-only: region incomplete -> rescan raw src/dst
            float bx, by;
            if (f32mode) {
                bx = ((const float*)biasp)[lane * 2];
                by = ((const float*)biasp)[lane * 2 + 1];
            } else {
                bx = bf16bits_to_f32(((const unsigned short*)biasp)[lane * 2]);
                by = bf16bits_to_f32(((const unsigned short*)biasp)[lane * 2 + 1]);
            }
            for (int nl = wave; nl < BKT_NODES; nl += AGG_THREADS / 64) {
                const int node = node0 + nl;
                if (node >= n_nodes) continue;
                float ax = 0.f, ay = 0.f;
                int deg = 0;
                for (int e = 0; e < n_edges; ++e) {
                    int d = i64 ? (int)((const long long*)dstp)[e]
                                : ((const int*)dstp)[e];
                    if (d == node) {
                        int s = i64 ? (int)((const long long*)srcp)[e]
                                    : ((const int*)srcp)[e];
                        if ((unsigned)s >= (unsigned)n_nodes) s = 0;
                        unsigned p = *(const unsigned*)(h + (size_t)s * F_OUT + lane * 2);
                        ax += bf16bits_to_f32((unsigned short)p);
                        ay += bf16bits_to_f32((unsigned short)(p >> 16));
                        deg++;
                    }
                }
                const float scale = 1.0f / fmaxf((float)deg, 1.0f);
                float ox = ax * scale + bx, oy = ay * scale + by;
                if (f32mode) {
                    ((float*)outp)[(size_t)node * F_OUT + lane * 2]     = ox;
                    ((float*)outp)[(size_t)node * F_OUT + lane * 2 + 1] = oy;
                } else {
                    unsigned pkv = ((unsigned)(unsigned short)f32_to_bf16_bits(oy) << 16) |
                                   (unsigned)(unsigned short)f32_to_bf16_bits(ox);
                    ((unsigned*)outp)[(size_t)node * (F_OUT / 2) + lane] = pkv;
                }
            }
            continue;
        }

        if (cnt > AGG_CAP) {
            // scan-filter the region per node (2-col per-lane layout)
            float bx, by;
            if (f32mode) {
                bx = ((const float*)biasp)[lane * 2];
                by = ((const float*)biasp)[lane * 2 + 1];
            } else {
                bx = bf16bits_to_f32(((const unsigned short*)biasp)[lane * 2]);
                by = bf16bits_to_f32(((const unsigned short*)biasp)[lane * 2 + 1]);
            }
            for (int nl = wave; nl < BKT_NODES; nl += AGG_THREADS / 64) {
                const int node = node0 + nl;
                if (node >= n_nodes) continue;
                float ax = 0.f, ay = 0.f;
                int deg = 0;
                for (int i = 0; i < cnt; ++i) {
                    const unsigned pk = bucket_edges[beg + i];
                    if ((int)(pk >> 24) == nl) {
                        const int s = (int)(pk & 0xFFFFFF);
                        unsigned p = *(const unsigned*)(h + (size_t)s * F_OUT + lane * 2);
                        ax += bf16bits_to_f32((unsigned short)p);
                        ay += bf16bits_to_f32((unsigned short)(p >> 16));
                        deg++;
                    }
                }
                const float scale = 1.0f / fmaxf((float)deg, 1.0f);
                float ox = ax * scale + bx, oy = ay * scale + by;
                if (f32mode) {
                    ((float*)outp)[(size_t)node * F_OUT + lane * 2]     = ox;
                    ((float*)outp)[(size_t)node * F_OUT + lane * 2 + 1] = oy;
                } else {
                    unsigned pkv = ((unsigned)(unsigned short)f32_to_bf16_bits(oy) << 16) |
                                   (unsigned)(unsigned short)f32_to_bf16_bits(ox);
                    ((unsigned*)outp)[(size_t)node * (F_OUT / 2) + lane] = pkv;
                }
            }
            continue;
        }

        __syncthreads();   // protect LDS from the previous iteration's readers

        // ---- LDS counting sort by local dst (256 bins) ----
        if (tid < BKT_NODES) hist[tid] = 0;
        if (tid == 0) node_cursor = 0;
        __syncthreads();
        for (int i = tid; i < cnt; i += AGG_THREADS)
            atomicAdd(&hist[bucket_edges[beg + i] >> 24], 1);
        __syncthreads();
        // wave-parallel exclusive bin scan (wave 0: 4 bins/lane + shfl_up)
        if (wave == 0) {
            const int b0 = lane * 4;
            const int h0 = hist[b0], h1 = hist[b0 + 1],
                      h2 = hist[b0 + 2], h3 = hist[b0 + 3];
            const int lsum = h0 + h1 + h2 + h3;
            int run = lsum;
#pragma unroll
            for (int off = 1; off < 64; off <<= 1) {
                int x = __shfl_up(run, off);
                if (lane >= off) run += x;
            }
            const int lexcl = run - lsum;
            excl[b0]     = lexcl;                cur2[b0]     = lexcl;
            excl[b0 + 1] = lexcl + h0;           cur2[b0 + 1] = lexcl + h0;
            excl[b0 + 2] = lexcl + h0 + h1;      cur2[b0 + 2] = lexcl + h0 + h1;
            excl[b0 + 3] = lexcl + h0 + h1 + h2; cur2[b0 + 3] = lexcl + h0 + h1 + h2;
        }
        __syncthreads();
        for (int i = tid; i < cnt; i += AGG_THREADS) {
            const unsigned pk = bucket_edges[beg + i];
            const int pos = atomicAdd(&cur2[pk >> 24], 1);
            s_src[pos] = (int)(pk & 0xFFFFFF);
        }
        __syncthreads();

        // ---- per-node accumulation, waves steal nodes from the LDS cursor ----
        for (;;) {
            int nl;
            if (lane == 0) nl = atomicAdd(&node_cursor, 1);
            nl = __shfl(nl, 0);
            if (nl >= BKT_NODES) break;
            const int node = node0 + nl;
            if (node >= n_nodes) continue;

            const int nbeg = excl[nl];
            const int ncnt = hist[nl];

            float acc[8];
#pragma unroll
            for (int j = 0; j < 8; ++j) acc[j] = 0.f;

            int i = 0;
            for (; i + 15 < ncnt; i += 16) {   // 16 edges/iter, 4 loads in flight
                const int s0 = s_src[nbeg + i + grp];
                const int s1 = s_src[nbeg + i + 4 + grp];
                const int s2 = s_src[nbeg + i + 8 + grp];
                const int s3 = s_src[nbeg + i + 12 + grp];
                const short8 v0 = *(const short8*)(h + (size_t)s0 * F_OUT + sub * 8);
                const short8 v1 = *(const short8*)(h + (size_t)s1 * F_OUT + sub * 8);
                const short8 v2 = *(const short8*)(h + (size_t)s2 * F_OUT + sub * 8);
                const short8 v3 = *(const short8*)(h + (size_t)s3 * F_OUT + sub * 8);
#pragma unroll
                for (int j = 0; j < 8; ++j) {
                    acc[j] += bf16bits_to_f32((unsigned short)v0[j]);
                    acc[j] += bf16bits_to_f32((unsigned short)v1[j]);
                    acc[j] += bf16bits_to_f32((unsigned short)v2[j]);
                    acc[j] += bf16bits_to_f32((unsigned short)v3[j]);
                }
            }
            for (; i + 7 < ncnt; i += 8) {     // 8 edges/iter, 2 loads
                const int s0 = s_src[nbeg + i + grp];
                const int s1 = s_src[nbeg + i + 4 + grp];
                const short8 v0 = *(const short8*)(h + (size_t)s0 * F_OUT + sub * 8);
                const short8 v1 = *(const short8*)(h + (size_t)s1 * F_OUT + sub * 8);
#pragma unroll
                for (int j = 0; j < 8; ++j) {
                    acc[j] += bf16bits_to_f32((unsigned short)v0[j]);
                    acc[j] += bf16bits_to_f32((unsigned short)v1[j]);
                }
            }
            for (; i < ncnt; i += 4) {          // predicated tail, 4 edges/iter
                const int e = i + grp;
                if (e < ncnt) {
                    const int s = s_src[nbeg + e];
                    const short8 v = *(const short8*)(h + (size_t)s * F_OUT + sub * 8);
#pragma unroll
                    for (int j = 0; j < 8; ++j)
                        acc[j] += bf16bits_to_f32((unsigned short)v[j]);
                }
            }

#pragma unroll
            for (int j = 0; j < 8; ++j) {
                acc[j] += __shfl_xor(acc[j], 16);
                acc[j] += __shfl_xor(acc[j], 32);
            }

            const float scale = 1.0f / fmaxf((float)ncnt, 1.0f);
            if (lane < 16) {
                if (f32mode) {
                    float* o = (float*)outp + (size_t)node * F_OUT + sub * 8;
                    floatx4 o0, o1;
#pragma unroll
                    for (int j = 0; j < 4; ++j) {
                        o0[j] = acc[j] * scale + bs[j];
                        o1[j] = acc[4 + j] * scale + bs[4 + j];
                    }
                    *(floatx4*)o = o0;
                    *(floatx4*)(o + 4) = o1;
                } else {
                    short8 r;
#pragma unroll
                    for (int j = 0; j < 8; ++j)
                        r[j] = f32_to_bf16_bits(acc[j] * scale + bs[j]);
                    *(short8*)((unsigned short*)outp + (size_t)node * F_OUT + sub * 8) = r;
                }
            }
        }
    }
}

extern "C" void kernel_launch(void* const* d_in, const int* in_sizes, int n_in,
                              void* d_out, int out_size, void* d_ws, size_t ws_size,
                              hipStream_t stream)
{
    const void* feat = d_in[0];
    const void* w    = d_in[1];
    const void* bias = d_in[2];
    const void* src  = d_in[3];
    const void* dst  = d_in[4];
    const int n_nodes = in_sizes[0] / F_IN;
    const int n_edges = in_sizes[3];
    const int nbkt = (n_nodes + BKT_NODES - 1) / BKT_NODES;  // 391 @ 100k

    // fixed per-bucket capacity ~ 2x mean, rounded up to 1024
    int cap = (int)((2LL * n_edges / nbkt + 1023) / 1024) * 1024;
    if (cap < 2048) cap = 2048;

    char* ws = (char*)d_ws;
    auto align256 = [](size_t x) { return (x + 255) & ~(size_t)255; };

    size_t off = 0;
    int* cursor = (int*)(ws + off);             off = align256(off + (size_t)nbkt * 4);
    unsigned* bucket_edges = (unsigned*)(ws + off);
    off = align256(off + (size_t)nbkt * cap * 4);
    unsigned short* hp = (unsigned short*)(ws + off);
    off = align256(off + (size_t)n_nodes * F_OUT * 2);
    // total ~38.6 MB @ 100k/1.6M

    const int n_tiles = (n_nodes + 63) / 64;
    const int gemm_blocks = min(512, n_tiles);
    gemm_kernel<<<gemm_blocks, GEMM_THREADS, 0, stream>>>(
        feat, w, hp, n_nodes, n_tiles, cursor, nbkt);

    binfill_kernel<<<FILL_BLOCKS, FILL_THREADS, 0, stream>>>(
        src, dst, cursor, bucket_edges, n_edges, n_nodes, nbkt, cap);

    const int agg_blocks = min(1024, nbkt);
    agg_kernel<<<agg_blocks, AGG_THREADS, 0, stream>>>(
        hp, bucket_edges, cursor, src, dst, n_edges, bias, d_out,
        n_nodes, nbkt, cap, feat);
}